// Round 5
// baseline (454.623 us; speedup 1.0000x reference)
//
#include <hip/hip_runtime.h>
#include <hip/hip_bf16.h>
#include <stdint.h>

// Problem constants (B, C, H, W, K) = (16, 64, 192, 192, 3)
#define NB 16
#define NC 64
#define NH 192
#define NW 192
#define NKDIM 576   // 9 taps * 64 ci, tap-major: k = tap*64 + ci

#define STRIP 12    // output rows per block (sliding window)
#define NSTEP 6     // STRIP / 2

typedef __bf16 bf16x8 __attribute__((ext_vector_type(8)));
typedef __bf16 bf16x4 __attribute__((ext_vector_type(4)));
typedef float  f32x4  __attribute__((ext_vector_type(4)));

static __device__ __forceinline__ __bf16 f2bf(float f) { return (__bf16)f; }

// ---------------------------------------------------------------------------
// Blend W0/W1 per batch into bf16, layout A[b][co][tap*64+ci] (tap-major K).
// ---------------------------------------------------------------------------
__global__ __launch_bounds__(256)
void blend_kernel(const float* __restrict__ W0, const float* __restrict__ W1,
                  const float* __restrict__ DoT, __bf16* __restrict__ A) {
    int idx = blockIdx.x * 256 + threadIdx.x;   // 16*64*576 total, exact grid
    int k   = idx % NKDIM;
    int co  = (idx / NKDIM) % NC;
    int b   = idx / (NKDIM * NC);
    int tap = k >> 6;
    int ci  = k & 63;
    float d  = DoT[b];
    int wi   = (co * NC + ci) * 9 + tap;
    float v  = (1.0f - d) * W0[wi] + d * W1[wi];
    A[idx] = f2bf(v);
}

// ---------------------------------------------------------------------------
// Pass 1: x NCHW fp32 -> xt NHWC bf16.  (verbatim from the verified version)
// ---------------------------------------------------------------------------
__global__ __launch_bounds__(256)
void nhwc_cvt_kernel(const float* __restrict__ x, __bf16* __restrict__ xt) {
    __shared__ float tile[64 * 68];   // 17408 B

    const int b  = blockIdx.z;
    const int h  = blockIdx.y;
    const int wt = blockIdx.x * 64;
    const int t  = threadIdx.x;

    {
        const int ci = t & 63;
        const int wq = t >> 6;
        const float* src = x + ((size_t)(b * NC + ci) * NH + h) * NW + wt;
        #pragma unroll
        for (int w4l = 0; w4l < 4; ++w4l) {
            const int w4 = wq * 4 + w4l;
            f32x4 v = *(const f32x4*)(src + w4 * 4);
            #pragma unroll
            for (int j = 0; j < 4; ++j)
                tile[(w4 * 4 + j) * 68 + ci] = v[j];
        }
    }
    __syncthreads();

    __bf16* dst = xt + ((size_t)(b * NH + h) * NW + wt) * NC;
    #pragma unroll
    for (int it = 0; it < 2; ++it) {
        const int c   = it * 256 + t;
        const int w   = c >> 3;
        const int cig = c & 7;
        f32x4 v0 = *(const f32x4*)&tile[w * 68 + cig * 8];
        f32x4 v1 = *(const f32x4*)&tile[w * 68 + cig * 8 + 4];
        bf16x8 pk = { f2bf(v0[0]), f2bf(v0[1]), f2bf(v0[2]), f2bf(v0[3]),
                      f2bf(v1[0]), f2bf(v1[1]), f2bf(v1[2]), f2bf(v1[3]) };
        *(bf16x8*)(dst + (size_t)w * NC + cig * 8) = pk;
    }
}

// ---------------------------------------------------------------------------
// Pass 2: sliding-window implicit-GEMM conv from NHWC bf16.
// Block = 512 thr (8 waves), owns (b, 64-w tile, 12-row strip); 6 steps of
// 2 output rows.  LDS = 6-slot row ring [slot][w 66][g' 8][8] bf16 (50688 B),
// swizzle g' = g ^ (w&7) (measured conflict-free, round 0).  Per step:
//   write prefetched 2 rows -> ring; barrier; issue next 2-row loads;
//   72 MFMA/wave on 4 resident rows; store 1 row/wave; barrier.
// Halo ratio 1.25 (15 staged rows / 12 output) vs round-0's 2.0, and the
// global loads overlap the MFMA phase.  Per-step footprint (17 KB rd + 32 KB
// wr) stays below round-0's, avoiding round-4's L2 working-set cliff.
// Ring safety: slot overwritten in step s last read in step s-1 or earlier,
// and separated by >=1 barrier (2 barriers/step).
// ---------------------------------------------------------------------------
__global__ __launch_bounds__(512, 4)
void conv_slide_kernel(const __bf16* __restrict__ xt, const __bf16* __restrict__ A,
                       float* __restrict__ out) {
    __shared__ __align__(16) __bf16 xs[6 * 66 * 64];   // 50688 B

    const int b  = blockIdx.z;
    const int h0 = blockIdx.y * STRIP;
    const int w0 = blockIdx.x * 64;

    const int tid  = threadIdx.x;
    const int lane = tid & 63;
    const int wave = tid >> 6;
    const int mt   = wave & 3;    // co tile
    const int nh   = wave >> 2;   // row within step (0/1)
    const int n    = lane & 15;
    const int quad = lane >> 4;

    const __bf16* xb = xt + (size_t)b * NH * NW * NC;

    // staging coords: main chunk = (row j, w = tid>>3, g = tid&7) -> 512/row
    const int sw_  = tid >> 3;            // 0..63
    const int sg_  = tid & 7;
    const int tlr_ = tid >> 4;            // tail: row offset 0/1 (tid<32)
    const int tw_  = 64 + ((tid >> 3) & 1);

    // row rel j (global row h0-1+j) load / ring-store helpers
    #define LDCHUNK(j, w, g, v)                                                 \
        {   const int gr_ = h0 - 1 + (j);                                       \
            const int gw_ = w0 - 1 + (w);                                       \
            v = (bf16x8){};                                                     \
            if (gr_ >= 0 && gr_ < NH && gw_ >= 0 && gw_ < NW)                   \
                v = *(const bf16x8*)(xb + ((size_t)gr_ * NW + gw_) * NC + (g) * 8); }
    #define STCHUNK(slot, w, g, v)                                              \
        *(bf16x8*)&xs[((((slot) * 66 + (w)) * 8) + ((g) ^ ((w) & 7))) * 8] = (v);

    // ---- prologue: stage rows rel 0..2 into slots 0..2 ----
    {
        #pragma unroll
        for (int it = 0; it < 3; ++it) {
            bf16x8 v; LDCHUNK(it, sw_, sg_, v);
            STCHUNK(it, sw_, sg_, v);
        }
        if (tid < 48) {
            const int j = tid >> 4;       // 0..2
            bf16x8 v; LDCHUNK(j, tw_, sg_, v);
            STCHUNK(j, tw_, sg_, v);
        }
    }

    // ---- A fragments: preload once per block (amortized over 6 steps) ----
    // A[m=lane&15][k=quad*8+j] (m89-verified), k = tap*64 + ch*32 + quad*8 + j
    const __bf16* Ap = A + ((size_t)b * NC + mt * 16 + n) * NKDIM + quad * 8;
    bf16x8 afr[9][2];
    #pragma unroll
    for (int tap = 0; tap < 9; ++tap)
        #pragma unroll
        for (int ch = 0; ch < 2; ++ch)
            afr[tap][ch] = *(const bf16x8*)(Ap + tap * 64 + ch * 32);

    // ---- prefetch rows rel 3,4 into registers ----
    bf16x8 r0_, r1_, rt_ = {};
    LDCHUNK(3, sw_, sg_, r0_);
    LDCHUNK(4, sw_, sg_, r1_);
    if (tid < 32) { LDCHUNK(3 + tlr_, tw_, sg_, rt_); }

    float* const ob0 = out + (size_t)b * NC * NH * NW + w0;

    // ---- 6 steps of 2 output rows ----
    #pragma unroll
    for (int s = 0; s < NSTEP; ++s) {
        // W(s): commit prefetched rows rel 2s+3, 2s+4 to ring
        STCHUNK((2 * s + 3) % 6, sw_, sg_, r0_);
        STCHUNK((2 * s + 4) % 6, sw_, sg_, r1_);
        if (tid < 32) { STCHUNK((2 * s + 3 + tlr_) % 6, tw_, sg_, rt_); }
        __syncthreads();                                   // B1: writes visible

        // issue next-step loads (rel 2s+5, 2s+6); overlap with MFMA below
        if (s < NSTEP - 1) {
            LDCHUNK(2 * s + 5, sw_, sg_, r0_);
            LDCHUNK(2 * s + 6, sw_, sg_, r1_);
            if (tid < 32) { LDCHUNK(2 * s + 5 + tlr_, tw_, sg_, rt_); }
        }

        // R(s): 9 taps x 2 ch x 4 nt = 72 MFMA; reads rel 2s .. 2s+3
        f32x4 acc[4];
        #pragma unroll
        for (int nt = 0; nt < 4; ++nt) acc[nt] = (f32x4){0.f, 0.f, 0.f, 0.f};

        #pragma unroll
        for (int tap = 0; tap < 9; ++tap) {
            const int dh   = tap / 3;
            const int dw   = tap - dh * 3;
            const int slot = (2 * s + nh + dh) % 6;        // nh runtime, rest folded
            #pragma unroll
            for (int nt = 0; nt < 4; ++nt) {
                const int wl   = dw + nt * 16 + n;
                const int sw   = wl & 7;
                const int base = ((slot * 66 + wl) * 8) * 8;
                bf16x8 b0 = *(const bf16x8*)&xs[base + ((0 * 4 + quad) ^ sw) * 8];
                acc[nt] = __builtin_amdgcn_mfma_f32_16x16x32_bf16(
                    afr[tap][0], b0, acc[nt], 0, 0, 0);
                bf16x8 b1 = *(const bf16x8*)&xs[base + ((1 * 4 + quad) ^ sw) * 8];
                acc[nt] = __builtin_amdgcn_mfma_f32_16x16x32_bf16(
                    afr[tap][1], b1, acc[nt], 0, 0, 0);
            }
        }

        // epilogue: row y = h0 + 2s + nh; D col=lane&15 (w), row=quad*4+reg (co)
        {
            const int y = h0 + 2 * s + nh;
            float* ob = ob0 + (size_t)y * NW;
            #pragma unroll
            for (int reg = 0; reg < 4; ++reg) {
                const int co = mt * 16 + quad * 4 + reg;
                float* orow = ob + (size_t)co * NH * NW;
                #pragma unroll
                for (int nt = 0; nt < 4; ++nt) {
                    orow[nt * 16 + n] = acc[nt][reg];
                }
            }
        }
        __syncthreads();                                   // B2: reads done before next W
    }
    #undef LDCHUNK
    #undef STCHUNK
}

// ---------------------------------------------------------------------------
// Fallback (verified single-pass NCHW kernel) if ws_size is too small for xt.
// ---------------------------------------------------------------------------
__global__ __launch_bounds__(512, 4)
void conv_nchw_kernel(const float* __restrict__ x, const __bf16* __restrict__ A,
                      float* __restrict__ out) {
    __shared__ __bf16 xs[4 * 66 * 72];

    const int b  = blockIdx.z;
    const int h0 = blockIdx.y * 2;
    const int w0 = blockIdx.x * 64;

    const int tid  = threadIdx.x;
    const int lane = tid & 63;
    const int wave = tid >> 6;

    {
        const int r  = tid >> 7;
        const int s  = tid & 127;
        const int gr = h0 - 1 + r;
        const bool rowok = (gr >= 0) && (gr < NH);
        const float* xb = x + (size_t)b * NC * NH * NW + (ptrdiff_t)gr * NW;

        #pragma unroll
        for (int j = 0; j < 8; ++j) {
            const int p   = j * 128 + s;
            const int wl  = p & 63;
            const int ci4 = p >> 6;
            const int gw  = w0 - 1 + wl;
            const bool ok = rowok && (gw >= 0);
            float v0 = ok ? xb[(size_t)(ci4 * 4 + 0) * NH * NW + gw] : 0.0f;
            float v1 = ok ? xb[(size_t)(ci4 * 4 + 1) * NH * NW + gw] : 0.0f;
            float v2 = ok ? xb[(size_t)(ci4 * 4 + 2) * NH * NW + gw] : 0.0f;
            float v3 = ok ? xb[(size_t)(ci4 * 4 + 3) * NH * NW + gw] : 0.0f;
            bf16x4 pk = { f2bf(v0), f2bf(v1), f2bf(v2), f2bf(v3) };
            const int g  = ci4 >> 1;
            const int gp = g ^ ((wl >> 3) & 7);
            *(bf16x4*)&xs[(r * 66 + wl) * 72 + gp * 8 + (ci4 & 1) * 4] = pk;
        }
        if (s < 32) {
            const int wl  = 64 + (s & 1);
            const int ci4 = s >> 1;
            const int gw  = w0 - 1 + wl;
            const bool ok = rowok && (gw < NW);
            float v0 = ok ? xb[(size_t)(ci4 * 4 + 0) * NH * NW + gw] : 0.0f;
            float v1 = ok ? xb[(size_t)(ci4 * 4 + 1) * NH * NW + gw] : 0.0f;
            float v2 = ok ? xb[(size_t)(ci4 * 4 + 2) * NH * NW + gw] : 0.0f;
            float v3 = ok ? xb[(size_t)(ci4 * 4 + 3) * NH * NW + gw] : 0.0f;
            bf16x4 pk = { f2bf(v0), f2bf(v1), f2bf(v2), f2bf(v3) };
            const int g  = ci4 >> 1;
            const int gp = g ^ ((wl >> 3) & 7);
            *(bf16x4*)&xs[(r * 66 + wl) * 72 + gp * 8 + (ci4 & 1) * 4] = pk;
        }
    }

    const int mt   = wave & 3;
    const int nh   = wave >> 2;
    const int n    = lane & 15;
    const int quad = lane >> 4;

    const __bf16* Ap = A + ((size_t)b * NC + mt * 16 + n) * NKDIM + quad * 8;
    bf16x8 afr[9][2];
    #pragma unroll
    for (int tap = 0; tap < 9; ++tap)
        #pragma unroll
        for (int ch = 0; ch < 2; ++ch)
            afr[tap][ch] = *(const bf16x8*)(Ap + tap * 64 + ch * 32);

    __syncthreads();

    f32x4 acc[4];
    #pragma unroll
    for (int nt = 0; nt < 4; ++nt) acc[nt] = (f32x4){0.f, 0.f, 0.f, 0.f};

    #pragma unroll
    for (int tap = 0; tap < 9; ++tap) {
        const int dh  = tap / 3;
        const int dw  = tap - dh * 3;
        const int row = nh + dh;
        #pragma unroll
        for (int ch = 0; ch < 2; ++ch) {
            const int g = ch * 4 + quad;
            #pragma unroll
            for (int nt = 0; nt < 4; ++nt) {
                const int wl = dw + nt * 16 + n;
                const int gp = g ^ ((wl >> 3) & 7);
                bf16x8 bfr = *(const bf16x8*)&xs[(row * 66 + wl) * 72 + gp * 8];
                acc[nt] = __builtin_amdgcn_mfma_f32_16x16x32_bf16(
                    afr[tap][ch], bfr, acc[nt], 0, 0, 0);
            }
        }
    }

    const int h = h0 + nh;
    float* ob = out + (size_t)b * NC * NH * NW + (size_t)h * NW + w0;
    #pragma unroll
    for (int reg = 0; reg < 4; ++reg) {
        const int co = mt * 16 + quad * 4 + reg;
        float* orow = ob + (size_t)co * NH * NW;
        #pragma unroll
        for (int nt = 0; nt < 4; ++nt) {
            orow[nt * 16 + n] = acc[nt][reg];
        }
    }
}

// ---------------------------------------------------------------------------
extern "C" void kernel_launch(void* const* d_in, const int* in_sizes, int n_in,
                              void* d_out, int out_size, void* d_ws, size_t ws_size,
                              hipStream_t stream) {
    const float* x   = (const float*)d_in[0];
    const float* DoT = (const float*)d_in[1];
    const float* W0  = (const float*)d_in[2];
    const float* W1  = (const float*)d_in[3];
    float* out = (float*)d_out;

    // Workspace layout: A (blended bf16 weights) then xt (NHWC bf16 x).
    const size_t A_BYTES  = (size_t)NB * NC * NKDIM * 2;          // 1,179,648
    const size_t XT_BYTES = (size_t)NB * NH * NW * NC * 2;        // 75,497,472
    __bf16* A  = (__bf16*)d_ws;
    __bf16* xt = (__bf16*)((char*)d_ws + A_BYTES);

    blend_kernel<<<dim3((NB * NC * NKDIM) / 256), 256, 0, stream>>>(W0, W1, DoT, A);

    if (ws_size >= A_BYTES + XT_BYTES) {
        nhwc_cvt_kernel<<<dim3(NW / 64, NH, NB), dim3(256), 0, stream>>>(x, xt);
        conv_slide_kernel<<<dim3(NW / 64, NH / STRIP, NB), dim3(512), 0, stream>>>(xt, A, out);
    } else {
        conv_nchw_kernel<<<dim3(NW / 64, NH / 2, NB), dim3(512), 0, stream>>>(x, A, out);
    }
}

// Round 6
// 370.996 us; speedup vs baseline: 1.2254x; 1.2254x over previous
//
#include <hip/hip_runtime.h>
#include <hip/hip_bf16.h>
#include <stdint.h>

// Problem constants (B, C, H, W, K) = (16, 64, 192, 192, 3)
#define NB 16
#define NC 64
#define NH 192
#define NW 192
#define NKDIM 576   // 9 taps * 64 ci, tap-major: k = tap*64 + ci

typedef __bf16 bf16x8 __attribute__((ext_vector_type(8)));
typedef __bf16 bf16x4 __attribute__((ext_vector_type(4)));
typedef float  f32x4  __attribute__((ext_vector_type(4)));

static __device__ __forceinline__ __bf16 f2bf(float f) { return (__bf16)f; }

// ---------------------------------------------------------------------------
// Blend W0/W1 per batch into bf16, layout A[b][co][tap*64+ci] (tap-major K).
// ---------------------------------------------------------------------------
__global__ __launch_bounds__(256)
void blend_kernel(const float* __restrict__ W0, const float* __restrict__ W1,
                  const float* __restrict__ DoT, __bf16* __restrict__ A) {
    int idx = blockIdx.x * 256 + threadIdx.x;   // 16*64*576 total, exact grid
    int k   = idx % NKDIM;
    int co  = (idx / NKDIM) % NC;
    int b   = idx / (NKDIM * NC);
    int tap = k >> 6;
    int ci  = k & 63;
    float d  = DoT[b];
    int wi   = (co * NC + ci) * 9 + tap;
    float v  = (1.0f - d) * W0[wi] + d * W1[wi];
    A[idx] = f2bf(v);
}

// ---------------------------------------------------------------------------
// Pass 1: x NCHW fp32 -> xt NHWC bf16.  Block = 256 thr, tile = 64 ci x 64 w
// for one (b,h).  LDS fp32 tile [w][ci] stride 68 (16B-aligned, bank-uniform).
// (verbatim from the verified 373us version)
// ---------------------------------------------------------------------------
__global__ __launch_bounds__(256)
void nhwc_cvt_kernel(const float* __restrict__ x, __bf16* __restrict__ xt) {
    __shared__ float tile[64 * 68];   // 17408 B

    const int b  = blockIdx.z;
    const int h  = blockIdx.y;
    const int wt = blockIdx.x * 64;
    const int t  = threadIdx.x;

    // read phase: thread (ci = t&63, wq = t>>6) loads 4 float4 along w
    {
        const int ci = t & 63;
        const int wq = t >> 6;
        const float* src = x + ((size_t)(b * NC + ci) * NH + h) * NW + wt;
        #pragma unroll
        for (int w4l = 0; w4l < 4; ++w4l) {
            const int w4 = wq * 4 + w4l;
            f32x4 v = *(const f32x4*)(src + w4 * 4);
            #pragma unroll
            for (int j = 0; j < 4; ++j)
                tile[(w4 * 4 + j) * 68 + ci] = v[j];
        }
    }
    __syncthreads();

    // write phase: chunk c -> (w = c>>3, cig = c&7); 8 ci -> bf16x8 store
    __bf16* dst = xt + ((size_t)(b * NH + h) * NW + wt) * NC;
    #pragma unroll
    for (int it = 0; it < 2; ++it) {
        const int c   = it * 256 + t;
        const int w   = c >> 3;
        const int cig = c & 7;
        f32x4 v0 = *(const f32x4*)&tile[w * 68 + cig * 8];
        f32x4 v1 = *(const f32x4*)&tile[w * 68 + cig * 8 + 4];
        bf16x8 pk = { f2bf(v0[0]), f2bf(v0[1]), f2bf(v0[2]), f2bf(v0[3]),
                      f2bf(v1[0]), f2bf(v1[1]), f2bf(v1[2]), f2bf(v1[3]) };
        *(bf16x8*)(dst + (size_t)w * NC + cig * 8) = pk;
    }
}

// ---------------------------------------------------------------------------
// Pass 2: implicit-GEMM conv from NHWC bf16.  EXACT round-0 373us structure
// (2 output rows/block, 4 staged rows, 64 co x 64 w, zero measured bank
// conflicts, FETCH ~= xt exactly, WRITE = out exactly) with ONE change:
// the A fragments afr[9][2] are pinned into registers via an opaque asm
// use after the preload.  Round-0's VGPR_Count=60 proved the compiler sank
// the A loads into the MFMA loop as dependent ~200cy L2 loads feeding only
// 4 MFMAs each -> predicted MfmaUtil ~16% == measured 14.8%.  Pinning makes
// them true register operands (72 VGPR, fits the 128 cap of (512,4)).
// ---------------------------------------------------------------------------
__global__ __launch_bounds__(512, 4)
void conv_nhwc_kernel(const __bf16* __restrict__ xt, const __bf16* __restrict__ A,
                      float* __restrict__ out) {
    __shared__ __bf16 xs[4 * 66 * 8 * 8];   // 33792 B

    const int b  = blockIdx.z;
    const int h0 = blockIdx.y * 2;
    const int w0 = blockIdx.x * 64;

    const int tid  = threadIdx.x;
    const int lane = tid & 63;
    const int wave = tid >> 6;

    // ---- stage 4 rows x 66 w x 64 ci (bf16, 16B chunks, swizzled) ----
    // 2112 chunks: chunk c -> r = c/528, w = (c%528)>>3, g = c&7
    {
        #pragma unroll
        for (int it = 0; it < 4; ++it) {
            const int c   = it * 512 + tid;
            const int r   = c / 528;
            const int rem = c - r * 528;
            const int w   = rem >> 3;
            const int g   = rem & 7;
            const int gr  = h0 - 1 + r;
            const int gw  = w0 - 1 + w;
            const bool ok = (gr >= 0) && (gr < NH) && (gw >= 0) && (gw < NW);
            bf16x8 v = {};
            if (ok)
                v = *(const bf16x8*)(xt + ((size_t)(b * NH + gr) * NW + gw) * NC + g * 8);
            *(bf16x8*)&xs[(((r * 66 + w) * 8) + (g ^ (w & 7))) * 8] = v;
        }
        if (tid < 64) {
            const int c   = 2048 + tid;
            const int r   = 3;
            const int rem = c - 3 * 528;
            const int w   = rem >> 3;
            const int g   = rem & 7;
            const int gr  = h0 + 2;
            const int gw  = w0 - 1 + w;
            const bool ok = (gr < NH) && (gw < NW);   // gr>=0, gw>=0 hold here
            bf16x8 v = {};
            if (ok)
                v = *(const bf16x8*)(xt + ((size_t)(b * NH + gr) * NW + gw) * NC + g * 8);
            *(bf16x8*)&xs[(((r * 66 + w) * 8) + (g ^ (w & 7))) * 8] = v;
        }
    }

    // ---- A prefetch: whole wave's weights into registers (L2-hot) ----
    const int mt   = wave & 3;    // co tile: co = mt*16 .. +16
    const int nh   = wave >> 2;   // output row 0/1
    const int n    = lane & 15;
    const int quad = lane >> 4;

    // A[m=lane&15][k=quad*8+j] (m89-verified), k = tap*64 + ch*32 + quad*8 + j
    const __bf16* Ap = A + ((size_t)b * NC + mt * 16 + n) * NKDIM + quad * 8;
    bf16x8 afr[9][2];
    #pragma unroll
    for (int tap = 0; tap < 9; ++tap)
        #pragma unroll
        for (int ch = 0; ch < 2; ++ch)
            afr[tap][ch] = *(const bf16x8*)(Ap + tap * 64 + ch * 32);

    // Pin fragments in registers: opaque read-write use means the loads
    // cannot be rematerialized inside the MFMA loop (round-0 pathology).
    #pragma unroll
    for (int tap = 0; tap < 9; ++tap)
        asm volatile("" : "+v"(afr[tap][0]), "+v"(afr[tap][1]));

    __syncthreads();

    // ---- MFMA main loop: 9 taps x 2 ch x 4 nt = 72 MFMA per wave ----
    f32x4 acc[4];
    #pragma unroll
    for (int nt = 0; nt < 4; ++nt) acc[nt] = (f32x4){0.f, 0.f, 0.f, 0.f};

    #pragma unroll
    for (int tap = 0; tap < 9; ++tap) {
        const int dh  = tap / 3;
        const int dw  = tap - dh * 3;
        const int row = nh + dh;
        #pragma unroll
        for (int ch = 0; ch < 2; ++ch) {
            #pragma unroll
            for (int nt = 0; nt < 4; ++nt) {
                const int wl = dw + nt * 16 + n;
                const int gp = (ch * 4 + quad) ^ (wl & 7);
                bf16x8 bfr = *(const bf16x8*)&xs[(((row * 66 + wl) * 8) + gp) * 8];
                acc[nt] = __builtin_amdgcn_mfma_f32_16x16x32_bf16(
                    afr[tap][ch], bfr, acc[nt], 0, 0, 0);
            }
        }
    }

    // ---- epilogue: D col=lane&15 (w), row=quad*4+reg (co within tile) ----
    const int h = h0 + nh;
    float* ob = out + (size_t)b * NC * NH * NW + (size_t)h * NW + w0;
    #pragma unroll
    for (int reg = 0; reg < 4; ++reg) {
        const int co = mt * 16 + quad * 4 + reg;
        float* orow = ob + (size_t)co * NH * NW;
        #pragma unroll
        for (int nt = 0; nt < 4; ++nt) {
            orow[nt * 16 + n] = acc[nt][reg];
        }
    }
}

// ---------------------------------------------------------------------------
// Fallback (verified single-pass NCHW kernel) if ws_size is too small for xt.
// ---------------------------------------------------------------------------
__global__ __launch_bounds__(512, 4)
void conv_nchw_kernel(const float* __restrict__ x, const __bf16* __restrict__ A,
                      float* __restrict__ out) {
    __shared__ __bf16 xs[4 * 66 * 72];

    const int b  = blockIdx.z;
    const int h0 = blockIdx.y * 2;
    const int w0 = blockIdx.x * 64;

    const int tid  = threadIdx.x;
    const int lane = tid & 63;
    const int wave = tid >> 6;

    {
        const int r  = tid >> 7;
        const int s  = tid & 127;
        const int gr = h0 - 1 + r;
        const bool rowok = (gr >= 0) && (gr < NH);
        const float* xb = x + (size_t)b * NC * NH * NW + (ptrdiff_t)gr * NW;

        #pragma unroll
        for (int j = 0; j < 8; ++j) {
            const int p   = j * 128 + s;
            const int wl  = p & 63;
            const int ci4 = p >> 6;
            const int gw  = w0 - 1 + wl;
            const bool ok = rowok && (gw >= 0);
            float v0 = ok ? xb[(size_t)(ci4 * 4 + 0) * NH * NW + gw] : 0.0f;
            float v1 = ok ? xb[(size_t)(ci4 * 4 + 1) * NH * NW + gw] : 0.0f;
            float v2 = ok ? xb[(size_t)(ci4 * 4 + 2) * NH * NW + gw] : 0.0f;
            float v3 = ok ? xb[(size_t)(ci4 * 4 + 3) * NH * NW + gw] : 0.0f;
            bf16x4 pk = { f2bf(v0), f2bf(v1), f2bf(v2), f2bf(v3) };
            const int g  = ci4 >> 1;
            const int gp = g ^ ((wl >> 3) & 7);
            *(bf16x4*)&xs[(r * 66 + wl) * 72 + gp * 8 + (ci4 & 1) * 4] = pk;
        }
        if (s < 32) {
            const int wl  = 64 + (s & 1);
            const int ci4 = s >> 1;
            const int gw  = w0 - 1 + wl;
            const bool ok = rowok && (gw < NW);
            float v0 = ok ? xb[(size_t)(ci4 * 4 + 0) * NH * NW + gw] : 0.0f;
            float v1 = ok ? xb[(size_t)(ci4 * 4 + 1) * NH * NW + gw] : 0.0f;
            float v2 = ok ? xb[(size_t)(ci4 * 4 + 2) * NH * NW + gw] : 0.0f;
            float v3 = ok ? xb[(size_t)(ci4 * 4 + 3) * NH * NW + gw] : 0.0f;
            bf16x4 pk = { f2bf(v0), f2bf(v1), f2bf(v2), f2bf(v3) };
            const int g  = ci4 >> 1;
            const int gp = g ^ ((wl >> 3) & 7);
            *(bf16x4*)&xs[(r * 66 + wl) * 72 + gp * 8 + (ci4 & 1) * 4] = pk;
        }
    }

    const int mt   = wave & 3;
    const int nh   = wave >> 2;
    const int n    = lane & 15;
    const int quad = lane >> 4;

    const __bf16* Ap = A + ((size_t)b * NC + mt * 16 + n) * NKDIM + quad * 8;
    bf16x8 afr[9][2];
    #pragma unroll
    for (int tap = 0; tap < 9; ++tap)
        #pragma unroll
        for (int ch = 0; ch < 2; ++ch)
            afr[tap][ch] = *(const bf16x8*)(Ap + tap * 64 + ch * 32);

    __syncthreads();

    f32x4 acc[4];
    #pragma unroll
    for (int nt = 0; nt < 4; ++nt) acc[nt] = (f32x4){0.f, 0.f, 0.f, 0.f};

    #pragma unroll
    for (int tap = 0; tap < 9; ++tap) {
        const int dh  = tap / 3;
        const int dw  = tap - dh * 3;
        const int row = nh + dh;
        #pragma unroll
        for (int ch = 0; ch < 2; ++ch) {
            const int g = ch * 4 + quad;
            #pragma unroll
            for (int nt = 0; nt < 4; ++nt) {
                const int wl = dw + nt * 16 + n;
                const int gp = g ^ ((wl >> 3) & 7);
                bf16x8 bfr = *(const bf16x8*)&xs[(row * 66 + wl) * 72 + gp * 8];
                acc[nt] = __builtin_amdgcn_mfma_f32_16x16x32_bf16(
                    afr[tap][ch], bfr, acc[nt], 0, 0, 0);
            }
        }
    }

    const int h = h0 + nh;
    float* ob = out + (size_t)b * NC * NH * NW + (size_t)h * NW + w0;
    #pragma unroll
    for (int reg = 0; reg < 4; ++reg) {
        const int co = mt * 16 + quad * 4 + reg;
        float* orow = ob + (size_t)co * NH * NW;
        #pragma unroll
        for (int nt = 0; nt < 4; ++nt) {
            orow[nt * 16 + n] = acc[nt][reg];
        }
    }
}

// ---------------------------------------------------------------------------
extern "C" void kernel_launch(void* const* d_in, const int* in_sizes, int n_in,
                              void* d_out, int out_size, void* d_ws, size_t ws_size,
                              hipStream_t stream) {
    const float* x   = (const float*)d_in[0];
    const float* DoT = (const float*)d_in[1];
    const float* W0  = (const float*)d_in[2];
    const float* W1  = (const float*)d_in[3];
    float* out = (float*)d_out;

    // Workspace layout: A (blended bf16 weights) then xt (NHWC bf16 x).
    const size_t A_BYTES  = (size_t)NB * NC * NKDIM * 2;          // 1,179,648
    const size_t XT_BYTES = (size_t)NB * NH * NW * NC * 2;        // 75,497,472
    __bf16* A  = (__bf16*)d_ws;
    __bf16* xt = (__bf16*)((char*)d_ws + A_BYTES);

    blend_kernel<<<dim3((NB * NC * NKDIM) / 256), 256, 0, stream>>>(W0, W1, DoT, A);

    if (ws_size >= A_BYTES + XT_BYTES) {
        nhwc_cvt_kernel<<<dim3(NW / 64, NH, NB), dim3(256), 0, stream>>>(x, xt);
        conv_nhwc_kernel<<<dim3(NW / 64, NH / 2, NB), dim3(512), 0, stream>>>(xt, A, out);
    } else {
        conv_nchw_kernel<<<dim3(NW / 64, NH / 2, NB), dim3(512), 0, stream>>>(x, A, out);
    }
}

// Round 8
// 346.260 us; speedup vs baseline: 1.3130x; 1.0714x over previous
//
#include <hip/hip_runtime.h>
#include <hip/hip_bf16.h>
#include <stdint.h>

// Problem constants (B, C, H, W, K) = (16, 64, 192, 192, 3)
#define NB 16
#define NC 64
#define NH 192
#define NW 192
#define NKDIM 576   // 9 taps * 64 ci, tap-major: k = tap*64 + ci

typedef __bf16 bf16x8 __attribute__((ext_vector_type(8)));
typedef __bf16 bf16x4 __attribute__((ext_vector_type(4)));
typedef float  f32x4  __attribute__((ext_vector_type(4)));

static __device__ __forceinline__ __bf16 f2bf(float f) { return (__bf16)f; }

// ---------------------------------------------------------------------------
// Blend W0/W1 per batch into bf16, layout A[b][co][tap*64+ci] (tap-major K).
// ---------------------------------------------------------------------------
__global__ __launch_bounds__(256)
void blend_kernel(const float* __restrict__ W0, const float* __restrict__ W1,
                  const float* __restrict__ DoT, __bf16* __restrict__ A) {
    int idx = blockIdx.x * 256 + threadIdx.x;   // 16*64*576 total, exact grid
    int k   = idx % NKDIM;
    int co  = (idx / NKDIM) % NC;
    int b   = idx / (NKDIM * NC);
    int tap = k >> 6;
    int ci  = k & 63;
    float d  = DoT[b];
    int wi   = (co * NC + ci) * 9 + tap;
    float v  = (1.0f - d) * W0[wi] + d * W1[wi];
    A[idx] = f2bf(v);
}

// ---------------------------------------------------------------------------
// Pass 1: x NCHW fp32 -> xt NHWC bf16.  Block = 256 thr, tile = 64 ci x 64 w.
// LDS tile is [ci][w] stride 65 so the GLOBAL READ is coalesced (lane = w;
// 64x4B contiguous per instr, 8 lines vs 64 scattered lines/instr of the
// old lane=ci layout).  Bank math: writes (ci*65+w)%32 = (ci+w)%32 -> 2-way
// (free, m136); reads ((cig*8+j)*65+w)%32 -> 2-way (free).  Write phase to
// xt unchanged (coalesced bf16x8).
// ---------------------------------------------------------------------------
__global__ __launch_bounds__(256)
void nhwc_cvt_kernel(const float* __restrict__ x, __bf16* __restrict__ xt) {
    __shared__ float tile[64 * 65];   // [ci][w], stride 65 f32, 16640 B

    const int b  = blockIdx.z;
    const int h  = blockIdx.y;
    const int wt = blockIdx.x * 64;
    const int t  = threadIdx.x;

    // read phase: lane w = t&63 (coalesced), ciq = t>>6; 16 scalar dwords
    {
        const int w   = t & 63;
        const int ciq = t >> 6;
        const float* src = x + ((size_t)(b * NC + ciq * 16) * NH + h) * NW + wt + w;
        #pragma unroll
        for (int j = 0; j < 16; ++j)
            tile[(ciq * 16 + j) * 65 + w] = src[(size_t)j * NH * NW];
    }
    __syncthreads();

    // write phase: chunk c -> (w = c>>3, cig = c&7); gather 8 ci -> bf16x8
    __bf16* dst = xt + ((size_t)(b * NH + h) * NW + wt) * NC;
    #pragma unroll
    for (int it = 0; it < 2; ++it) {
        const int c   = it * 256 + t;
        const int w   = c >> 3;
        const int cig = c & 7;
        float v0 = tile[(cig * 8 + 0) * 65 + w];
        float v1 = tile[(cig * 8 + 1) * 65 + w];
        float v2 = tile[(cig * 8 + 2) * 65 + w];
        float v3 = tile[(cig * 8 + 3) * 65 + w];
        float v4 = tile[(cig * 8 + 4) * 65 + w];
        float v5 = tile[(cig * 8 + 5) * 65 + w];
        float v6 = tile[(cig * 8 + 6) * 65 + w];
        float v7 = tile[(cig * 8 + 7) * 65 + w];
        bf16x8 pk = { f2bf(v0), f2bf(v1), f2bf(v2), f2bf(v3),
                      f2bf(v4), f2bf(v5), f2bf(v6), f2bf(v7) };
        *(bf16x8*)(dst + (size_t)w * NC + cig * 8) = pk;
    }
}

// ---------------------------------------------------------------------------
// Pass 2: implicit-GEMM conv from NHWC bf16.  EXACT round-0 373us structure
// (2 output rows/block, 4 staged rows, 64 co x 64 w, zero bank conflicts,
// FETCH ~= xt, WRITE = out exactly) with ONE change: A fragments use a
// 2-deep rotation (a0,a1 + next-tap prefetch = 16 VGPR, proven to stay
// register-resident at VGPR=64 in rounds 4/5 compiles) instead of the
// afr[9][2] array (which the allocator refuses to keep resident: round-0
// VGPR=60, round-6 pin attempt VGPR=56 -> per-tap dependent ~200cy L2 loads
// feeding only 4 MFMAs each).  Next-tap loads issue before the current
// tap's 8 MFMAs + 8 ds_reads (~140cy), hiding most of the A latency.
// ---------------------------------------------------------------------------
__global__ __launch_bounds__(512, 4)
void conv_nhwc_kernel(const __bf16* __restrict__ xt, const __bf16* __restrict__ A,
                      float* __restrict__ out) {
    __shared__ __bf16 xs[4 * 66 * 8 * 8];   // 33792 B

    const int b  = blockIdx.z;
    const int h0 = blockIdx.y * 2;
    const int w0 = blockIdx.x * 64;

    const int tid  = threadIdx.x;
    const int lane = tid & 63;
    const int wave = tid >> 6;

    // ---- stage 4 rows x 66 w x 64 ci (bf16, 16B chunks, swizzled) ----
    // 2112 chunks: chunk c -> r = c/528, w = (c%528)>>3, g = c&7
    {
        #pragma unroll
        for (int it = 0; it < 4; ++it) {
            const int c   = it * 512 + tid;
            const int r   = c / 528;
            const int rem = c - r * 528;
            const int w   = rem >> 3;
            const int g   = rem & 7;
            const int gr  = h0 - 1 + r;
            const int gw  = w0 - 1 + w;
            const bool ok = (gr >= 0) && (gr < NH) && (gw >= 0) && (gw < NW);
            bf16x8 v = {};
            if (ok)
                v = *(const bf16x8*)(xt + ((size_t)(b * NH + gr) * NW + gw) * NC + g * 8);
            *(bf16x8*)&xs[(((r * 66 + w) * 8) + (g ^ (w & 7))) * 8] = v;
        }
        if (tid < 64) {
            const int c   = 2048 + tid;
            const int r   = 3;
            const int rem = c - 3 * 528;
            const int w   = rem >> 3;
            const int g   = rem & 7;
            const int gr  = h0 + 2;
            const int gw  = w0 - 1 + w;
            const bool ok = (gr < NH) && (gw < NW);   // gr>=0, gw>=0 hold here
            bf16x8 v = {};
            if (ok)
                v = *(const bf16x8*)(xt + ((size_t)(b * NH + gr) * NW + gw) * NC + g * 8);
            *(bf16x8*)&xs[(((r * 66 + w) * 8) + (g ^ (w & 7))) * 8] = v;
        }
    }

    // ---- per-wave geometry ----
    const int mt   = wave & 3;    // co tile: co = mt*16 .. +16
    const int nh   = wave >> 2;   // output row 0/1
    const int n    = lane & 15;
    const int quad = lane >> 4;

    // A[m=lane&15][k=quad*8+j] (m89-verified), k = tap*64 + ch*32 + quad*8 + j
    const __bf16* Ap = A + ((size_t)b * NC + mt * 16 + n) * NKDIM + quad * 8;
    bf16x8 a0 = *(const bf16x8*)(Ap + 0);
    bf16x8 a1 = *(const bf16x8*)(Ap + 32);

    f32x4 acc[4];
    #pragma unroll
    for (int nt = 0; nt < 4; ++nt) acc[nt] = (f32x4){0.f, 0.f, 0.f, 0.f};

    __syncthreads();

    // ---- MFMA main loop: 9 taps x 2 ch x 4 nt = 72 MFMA per wave ----
    #pragma unroll
    for (int tap = 0; tap < 9; ++tap) {
        const int tn = (tap < 8) ? tap + 1 : 8;         // next-tap prefetch
        const bf16x8 na0 = *(const bf16x8*)(Ap + tn * 64);
        const bf16x8 na1 = *(const bf16x8*)(Ap + tn * 64 + 32);

        const int dh  = tap / 3;
        const int dw  = tap - dh * 3;
        const int row = nh + dh;
        #pragma unroll
        for (int nt = 0; nt < 4; ++nt) {
            const int wl = dw + nt * 16 + n;
            const int sw = wl & 7;
            const int base = ((row * 66 + wl) * 8) * 8;
            bf16x8 b0 = *(const bf16x8*)&xs[base + ((0 * 4 + quad) ^ sw) * 8];
            acc[nt] = __builtin_amdgcn_mfma_f32_16x16x32_bf16(
                a0, b0, acc[nt], 0, 0, 0);
            bf16x8 b1 = *(const bf16x8*)&xs[base + ((1 * 4 + quad) ^ sw) * 8];
            acc[nt] = __builtin_amdgcn_mfma_f32_16x16x32_bf16(
                a1, b1, acc[nt], 0, 0, 0);
        }
        a0 = na0; a1 = na1;
    }

    // ---- epilogue: D col=lane&15 (w), row=quad*4+reg (co within tile) ----
    const int h = h0 + nh;
    float* ob = out + (size_t)b * NC * NH * NW + (size_t)h * NW + w0;
    #pragma unroll
    for (int reg = 0; reg < 4; ++reg) {
        const int co = mt * 16 + quad * 4 + reg;
        float* orow = ob + (size_t)co * NH * NW;
        #pragma unroll
        for (int nt = 0; nt < 4; ++nt) {
            orow[nt * 16 + n] = acc[nt][reg];
        }
    }
}

// ---------------------------------------------------------------------------
// Fallback (verified single-pass NCHW kernel) if ws_size is too small for xt.
// ---------------------------------------------------------------------------
__global__ __launch_bounds__(512, 4)
void conv_nchw_kernel(const float* __restrict__ x, const __bf16* __restrict__ A,
                      float* __restrict__ out) {
    __shared__ __bf16 xs[4 * 66 * 72];

    const int b  = blockIdx.z;
    const int h0 = blockIdx.y * 2;
    const int w0 = blockIdx.x * 64;

    const int tid  = threadIdx.x;
    const int lane = tid & 63;
    const int wave = tid >> 6;

    {
        const int r  = tid >> 7;
        const int s  = tid & 127;
        const int gr = h0 - 1 + r;
        const bool rowok = (gr >= 0) && (gr < NH);
        const float* xb = x + (size_t)b * NC * NH * NW + (ptrdiff_t)gr * NW;

        #pragma unroll
        for (int j = 0; j < 8; ++j) {
            const int p   = j * 128 + s;
            const int wl  = p & 63;
            const int ci4 = p >> 6;
            const int gw  = w0 - 1 + wl;
            const bool ok = rowok && (gw >= 0);
            float v0 = ok ? xb[(size_t)(ci4 * 4 + 0) * NH * NW + gw] : 0.0f;
            float v1 = ok ? xb[(size_t)(ci4 * 4 + 1) * NH * NW + gw] : 0.0f;
            float v2 = ok ? xb[(size_t)(ci4 * 4 + 2) * NH * NW + gw] : 0.0f;
            float v3 = ok ? xb[(size_t)(ci4 * 4 + 3) * NH * NW + gw] : 0.0f;
            bf16x4 pk = { f2bf(v0), f2bf(v1), f2bf(v2), f2bf(v3) };
            const int g  = ci4 >> 1;
            const int gp = g ^ ((wl >> 3) & 7);
            *(bf16x4*)&xs[(r * 66 + wl) * 72 + gp * 8 + (ci4 & 1) * 4] = pk;
        }
        if (s < 32) {
            const int wl  = 64 + (s & 1);
            const int ci4 = s >> 1;
            const int gw  = w0 - 1 + wl;
            const bool ok = rowok && (gw < NW);
            float v0 = ok ? xb[(size_t)(ci4 * 4 + 0) * NH * NW + gw] : 0.0f;
            float v1 = ok ? xb[(size_t)(ci4 * 4 + 1) * NH * NW + gw] : 0.0f;
            float v2 = ok ? xb[(size_t)(ci4 * 4 + 2) * NH * NW + gw] : 0.0f;
            float v3 = ok ? xb[(size_t)(ci4 * 4 + 3) * NH * NW + gw] : 0.0f;
            bf16x4 pk = { f2bf(v0), f2bf(v1), f2bf(v2), f2bf(v3) };
            const int g  = ci4 >> 1;
            const int gp = g ^ ((wl >> 3) & 7);
            *(bf16x4*)&xs[(r * 66 + wl) * 72 + gp * 8 + (ci4 & 1) * 4] = pk;
        }
    }

    const int mt   = wave & 3;
    const int nh   = wave >> 2;
    const int n    = lane & 15;
    const int quad = lane >> 4;

    const __bf16* Ap = A + ((size_t)b * NC + mt * 16 + n) * NKDIM + quad * 8;
    bf16x8 afr[9][2];
    #pragma unroll
    for (int tap = 0; tap < 9; ++tap)
        #pragma unroll
        for (int ch = 0; ch < 2; ++ch)
            afr[tap][ch] = *(const bf16x8*)(Ap + tap * 64 + ch * 32);

    __syncthreads();

    f32x4 acc[4];
    #pragma unroll
    for (int nt = 0; nt < 4; ++nt) acc[nt] = (f32x4){0.f, 0.f, 0.f, 0.f};

    #pragma unroll
    for (int tap = 0; tap < 9; ++tap) {
        const int dh  = tap / 3;
        const int dw  = tap - dh * 3;
        const int row = nh + dh;
        #pragma unroll
        for (int ch = 0; ch < 2; ++ch) {
            const int g = ch * 4 + quad;
            #pragma unroll
            for (int nt = 0; nt < 4; ++nt) {
                const int wl = dw + nt * 16 + n;
                const int gp = g ^ ((wl >> 3) & 7);
                bf16x8 bfr = *(const bf16x8*)&xs[(row * 66 + wl) * 72 + gp * 8];
                acc[nt] = __builtin_amdgcn_mfma_f32_16x16x32_bf16(
                    afr[tap][ch], bfr, acc[nt], 0, 0, 0);
            }
        }
    }

    const int h = h0 + nh;
    float* ob = out + (size_t)b * NC * NH * NW + (size_t)h * NW + w0;
    #pragma unroll
    for (int reg = 0; reg < 4; ++reg) {
        const int co = mt * 16 + quad * 4 + reg;
        float* orow = ob + (size_t)co * NH * NW;
        #pragma unroll
        for (int nt = 0; nt < 4; ++nt) {
            orow[nt * 16 + n] = acc[nt][reg];
        }
    }
}

// ---------------------------------------------------------------------------
extern "C" void kernel_launch(void* const* d_in, const int* in_sizes, int n_in,
                              void* d_out, int out_size, void* d_ws, size_t ws_size,
                              hipStream_t stream) {
    const float* x   = (const float*)d_in[0];
    const float* DoT = (const float*)d_in[1];
    const float* W0  = (const float*)d_in[2];
    const float* W1  = (const float*)d_in[3];
    float* out = (float*)d_out;

    // Workspace layout: A (blended bf16 weights) then xt (NHWC bf16 x).
    const size_t A_BYTES  = (size_t)NB * NC * NKDIM * 2;          // 1,179,648
    const size_t XT_BYTES = (size_t)NB * NH * NW * NC * 2;        // 75,497,472
    __bf16* A  = (__bf16*)d_ws;
    __bf16* xt = (__bf16*)((char*)d_ws + A_BYTES);

    blend_kernel<<<dim3((NB * NC * NKDIM) / 256), 256, 0, stream>>>(W0, W1, DoT, A);

    if (ws_size >= A_BYTES + XT_BYTES) {
        nhwc_cvt_kernel<<<dim3(NW / 64, NH, NB), dim3(256), 0, stream>>>(x, xt);
        conv_nhwc_kernel<<<dim3(NW / 64, NH / 2, NB), dim3(512), 0, stream>>>(xt, A, out);
    } else {
        conv_nchw_kernel<<<dim3(NW / 64, NH / 2, NB), dim3(512), 0, stream>>>(x, A, out);
    }
}